// Round 8
// baseline (76.309 us; speedup 1.0000x reference)
//
#include <hip/hip_runtime.h>
#include <math.h>

#define MROWS 32768   // B*T
#define DDIM  1024
#define EDIM  64
#define TILEM 64      // rows per block
// WS: 64 chunks of 16-k, each 4096 halves (8 KB), frag-linear (verified R4-R7):
//   half index = c*4096 + nf*512 + lane*8 + j  (+2048 for lo plane)
//   B frag (32x32x16): col = nf*32 + (lane&31), k = (lane>>5)*8 + j
//   nf: 0,1 = route col-halves; 2,3 = noise col-halves

typedef _Float16 f16x8 __attribute__((ext_vector_type(8)));
typedef float    f32x16 __attribute__((ext_vector_type(16)));

__global__ __launch_bounds__(256)
void convW_kernel(const float* __restrict__ Wr, const float* __restrict__ Wn,
                  unsigned short* __restrict__ ws) {
    int gid = blockIdx.x * 256 + threadIdx.x;   // 131072 total
    int c32 = gid & 31;
    int j   = (gid >> 5) & 7;
    int lhi = (gid >> 8) & 1;
    int nf  = (gid >> 9) & 3;
    int c   = gid >> 11;
    int lane = lhi * 32 + c32;
    int k   = c * 16 + lhi * 8 + j;
    int col = nf * 32 + c32;                    // 0..63 route, 64..127 noise
    float w = (col < EDIM) ? Wr[k * EDIM + col] : Wn[k * EDIM + (col - EDIM)];
    _Float16 hi = (_Float16)w;
    _Float16 lo = (_Float16)((w - (float)hi) * 2048.0f);
    union { _Float16 h; unsigned short u; } cv;
    size_t base = (size_t)c * 4096 + nf * 512 + lane * 8 + j;
    cv.h = hi; ws[base]        = cv.u;
    cv.h = lo; ws[base + 2048] = cv.u;
}

__global__ __launch_bounds__(512, 4)
void router_mfma(const float* __restrict__ X,
                 const unsigned short* __restrict__ WS,
                 const float* __restrict__ br_g,
                 const float* __restrict__ bn_g,
                 const float* __restrict__ U,
                 float* __restrict__ out)
{
    __shared__ float P[4 * 2 * 1024];   // split-K partials: [wm*2+wn][plane][32r][32c] = 32 KB
    __shared__ float NZ[64 * 66];       // noisy-logit exchange tile

    const int t    = threadIdx.x;
    const int lane = t & 63;
    const int w    = t >> 6;       // 0..7
    const int wm   = w & 1;        // row-group (32 rows)
    const int wn   = (w >> 1) & 1; // col-half
    const int km   = w >> 2;       // k-half
    const int rowBase = blockIdx.x * TILEM;
    const int myRow = rowBase + wm * 32 + (lane & 31);
    const int kSub  = (lane >> 5) * 8;
    const float* xp = X + (size_t)myRow * DDIM + km * 512 + kSub;
    const unsigned short* bp = WS + (size_t)km * 32 * 4096 + wn * 512 + lane * 8;

    f32x16 aR0, aR1, aN0, aN1;
#pragma unroll
    for (int i = 0; i < 16; ++i) { aR0[i] = 0.f; aR1[i] = 0.f; aN0[i] = 0.f; aN1[i] = 0.f; }

    auto convA8 = [&](const float4& a, const float4& b, f16x8& hi, f16x8& lo) {
        float x[8] = {a.x, a.y, a.z, a.w, b.x, b.y, b.z, b.w};
#pragma unroll
        for (int j = 0; j < 8; ++j) {
            _Float16 h = (_Float16)x[j];
            hi[j] = h;
            lo[j] = (_Float16)((x[j] - (float)h) * 2048.0f);
        }
    };

    // ---- barrier-free K loop: 32 chunks of 16-k per wave ----
    float4 x0 = *(const float4*)(xp);
    float4 x1 = *(const float4*)(xp + 4);
    for (int c = 0; c < 32; ++c) {
        float4 nx0, nx1;
        if (c + 1 < 32) {
            nx0 = *(const float4*)(xp + (c + 1) * 16);
            nx1 = *(const float4*)(xp + (c + 1) * 16 + 4);
        }
        const unsigned short* bc = bp + (size_t)c * 4096;
        f16x8 bhiR = *(const f16x8*)(bc);
        f16x8 bloR = *(const f16x8*)(bc + 2048);
        f16x8 bhiN = *(const f16x8*)(bc + 1024);
        f16x8 bloN = *(const f16x8*)(bc + 3072);
        f16x8 ahi, alo;
        convA8(x0, x1, ahi, alo);
        aR0 = __builtin_amdgcn_mfma_f32_32x32x16_f16(ahi, bhiR, aR0, 0, 0, 0);
        aR1 = __builtin_amdgcn_mfma_f32_32x32x16_f16(ahi, bloR, aR1, 0, 0, 0);
        aR1 = __builtin_amdgcn_mfma_f32_32x32x16_f16(alo, bhiR, aR1, 0, 0, 0);
        aN0 = __builtin_amdgcn_mfma_f32_32x32x16_f16(ahi, bhiN, aN0, 0, 0, 0);
        aN1 = __builtin_amdgcn_mfma_f32_32x32x16_f16(ahi, bloN, aN1, 0, 0, 0);
        aN1 = __builtin_amdgcn_mfma_f32_32x32x16_f16(alo, bhiN, aN1, 0, 0, 0);
        x0 = nx0; x1 = nx1;
    }

    // ---- split-K reduction through LDS ----
    const float inv2048 = 1.0f / 2048.0f;
    float* Pw = P + (size_t)(wm * 2 + wn) * 2048;
    if (km == 1) {
#pragma unroll
        for (int reg = 0; reg < 16; ++reg) {
            int r = (reg & 3) + 8 * (reg >> 2) + 4 * (lane >> 5);
            int c = lane & 31;
            Pw[r * 32 + c]        = aR0[reg] + aR1[reg] * inv2048;
            Pw[1024 + r * 32 + c] = aN0[reg] + aN1[reg] * inv2048;
        }
    }
    __syncthreads();

    if (km == 0) {
        const int c0   = lane & 31;
        const int eCol = wn * 32 + c0;
        const float brv = br_g[eCol];
        const float bnv = bn_g[eCol];
#pragma unroll
        for (int reg = 0; reg < 16; ++reg) {
            int r    = (reg & 3) + 8 * (reg >> 2) + 4 * (lane >> 5);
            int lrow = wm * 32 + r;
            int grow = rowBase + lrow;
            float vR = aR0[reg] + aR1[reg] * inv2048 + Pw[r * 32 + c0];
            float vN = aN0[reg] + aN1[reg] * inv2048 + Pw[1024 + r * 32 + c0];
            float u  = U[(size_t)grow * EDIM + eCol];
            NZ[lrow * 66 + eCol] = (vR + brv) + u * log1pf(expf(vN + bnv));
        }
    }
    __syncthreads();

    // ---- butterfly top-2 + writes: 8 rows per wave ----
#pragma unroll 2
    for (int r = 0; r < 8; ++r) {
        int lrow = w * 8 + r;
        int grow = rowBase + lrow;
        float noisy = NZ[lrow * 66 + lane];

        float m1 = noisy; int i1 = lane;
        float m2 = -INFINITY; int i2 = 64;
#pragma unroll
        for (int s = 1; s < 64; s <<= 1) {
            float om1 = __shfl_xor(m1, s); int oi1 = __shfl_xor(i1, s);
            float om2 = __shfl_xor(m2, s); int oi2 = __shfl_xor(i2, s);
            bool aw = (m1 > om1) || (m1 == om1 && i1 < oi1);
            float w1  = aw ? m1 : om1;  int wi1  = aw ? i1 : oi1;
            float c2a = aw ? m2 : om2;  int c2ai = aw ? i2 : oi2;
            float c2b = aw ? om1 : m1;  int c2bi = aw ? oi1 : i1;
            bool bw = (c2b > c2a) || (c2b == c2a && c2bi < c2ai);
            m1 = w1; i1 = wi1;
            m2 = bw ? c2b : c2a;
            i2 = bw ? c2bi : c2ai;
        }
        float e2  = expf(m2 - m1);
        float inv = 1.0f / (1.0f + e2);
        float p   = (lane == i1) ? inv : ((lane == i2) ? e2 * inv : 0.0f);
        out[(size_t)grow * EDIM + lane] = p;
        if (lane < 2)
            out[(size_t)MROWS * EDIM + (size_t)grow * 2 + lane] =
                (float)(lane == 0 ? i1 : i2);
    }
}

extern "C" void kernel_launch(void* const* d_in, const int* in_sizes, int n_in,
                              void* d_out, int out_size, void* d_ws, size_t ws_size,
                              hipStream_t stream) {
    const float* X  = (const float*)d_in[0];  // mh_output [8,4096,1024]
    const float* Wr = (const float*)d_in[1];  // W_route   [1024,64]
    const float* br = (const float*)d_in[2];  // b_route   [64]
    const float* Wn = (const float*)d_in[3];  // W_noise   [1024,64]
    const float* bn = (const float*)d_in[4];  // b_noise   [64]
    const float* U  = (const float*)d_in[5];  // noise_u   [8,4096,64]
    (void)in_sizes; (void)n_in; (void)ws_size; // uses 512 KB of d_ws
    unsigned short* ws16 = (unsigned short*)d_ws;
    convW_kernel<<<512, 256, 0, stream>>>(Wr, Wn, ws16);
    router_mfma<<<MROWS / TILEM, 512, 0, stream>>>(X, ws16, br, bn, U, (float*)d_out);
}